// Round 6
// baseline (923.851 us; speedup 1.0000x reference)
//
#include <hip/hip_runtime.h>
#include <hip/hip_bf16.h>
#include <cstddef>

#define OBS_LEN  20
#define PRED_LEN 30

typedef __attribute__((ext_vector_type(8))) short short8v;  // 8 bf16 (4 VGPRs)
typedef __attribute__((ext_vector_type(4))) float f32x4;

__device__ __forceinline__ float sigm(float x) {
    return __builtin_amdgcn_rcpf(1.0f + __expf(-x));
}
__device__ __forceinline__ float tanh_f(float x) {
    return fmaf(2.0f, sigm(2.0f * x), -1.0f);
}
__device__ __forceinline__ unsigned short f2bf(float x) {  // RNE
    __hip_bfloat16 h = __float2bfloat16(x);
    return __builtin_bit_cast(unsigned short, h);
}
__device__ __forceinline__ float bf2f(unsigned short u) {
    unsigned v = ((unsigned)u) << 16;
    return __builtin_bit_cast(float, v);
}
// load 8 consecutive f32 from a weight row, convert to bf16x8 fragment
__device__ __forceinline__ short8v ldw8(const float* __restrict__ p) {
    const float4 a = *(const float4*)(p);
    const float4 b = *(const float4*)(p + 4);
    short8v r;
    r[0] = (short)f2bf(a.x); r[1] = (short)f2bf(a.y);
    r[2] = (short)f2bf(a.z); r[3] = (short)f2bf(a.w);
    r[4] = (short)f2bf(b.x); r[5] = (short)f2bf(b.y);
    r[6] = (short)f2bf(b.z); r[7] = (short)f2bf(b.w);
    return r;
}

#define MFMA(A, B, C) __builtin_amdgcn_mfma_f32_16x16x32_bf16((A), (B), (C), 0, 0, 0)

// Block: 256 threads = 4 waves, 16 batch rows.
// Wave w owns gate columns t*64 + w*16 + (lane&15) for gate types t=0..3
// -> each lane holds i,f,g,o for the SAME (batch,j): elementwise is in-register.
// Weights stay in VGPRs as B-fragments for the whole kernel (loaded once).
// h recurrence: bf16 hi + lo residual through LDS (lo pass reuses Whh frags).
// LDS padded to ~35.8KB: caps occupancy at exactly 4 blocks/CU -> regalloc
// targets 4 waves/EU -> 128-VGPR budget >= our 116 -> no spill, and we get
// 4 waves/SIMD (R5 had 2 via 55KB pad: latency-bound at Occ 23%).
extern "C" __global__ void __launch_bounds__(256)
traj_mfma(const float* __restrict__ obs,   const float* __restrict__ noise,
          const float* __restrict__ scene,
          const float* __restrict__ W_emb, const float* __restrict__ b_emb,
          const float* __restrict__ Wih_e, const float* __restrict__ Whh_e, const float* __restrict__ b_e,
          const float* __restrict__ W_h,   const float* __restrict__ b_h,
          const float* __restrict__ W_c,   const float* __restrict__ b_c,
          const float* __restrict__ Wih_d, const float* __restrict__ Whh_d, const float* __restrict__ b_d,
          const float* __restrict__ W_out, const float* __restrict__ b_out,
          float* __restrict__ out)
{
    __shared__ __align__(16) unsigned short hbuf[2][2][16 * 72]; // [buf][hi/lo], row stride 72 bf16
    __shared__ __align__(16) unsigned short e_l[16 * 40];        // e tile, stride 40 bf16
    __shared__ __align__(16) unsigned short ns_l[16 * 96];       // [noise16|scene64|zero16]
    __shared__ __align__(16) float obs_l[640];                   // 16 rows x 40 f32
    __shared__ __align__(16) float y_part[16 * 8];               // [i][w*2+c]
    __shared__ float occ_pad[5000];                              // occupancy clamp -> 4 blocks/CU

    const int id = threadIdx.x;
    // keep occ_pad alive (never executes: grid is 4096 blocks)
    if (blockIdx.x == 0xFFFFFFFFu) { occ_pad[id] = 1.0f; out[id] = occ_pad[id ^ 1]; }

    const int l    = id & 63;
    const int w    = id >> 6;        // wave = n-tile slot
    const int q    = l >> 4;
    const int jm   = l & 15;
    const int colb = w * 16 + jm;    // j in [0,64)
    const int bb   = blockIdx.x * 16;

    // ---------------- one-time register-resident weights ----------------
    short8v Be[3][4], Bd[3][4];
    float bias_e[4], bias_d[4];
#pragma unroll
    for (int t = 0; t < 4; ++t) {
        const int row = t * 64 + colb;                 // PyTorch gate row
        Be[0][t] = ldw8(Wih_e + row * 32 + 8 * q);     // k 0..31  (e)
        Be[1][t] = ldw8(Whh_e + row * 64 + 8 * q);     // k 32..63 (h lo half)
        Be[2][t] = ldw8(Whh_e + row * 64 + 32 + 8 * q);// k 64..95 (h hi half)
        Bd[0][t] = ldw8(Wih_d + row * 32 + 8 * q);
        Bd[1][t] = ldw8(Whh_d + row * 64 + 8 * q);
        Bd[2][t] = ldw8(Whh_d + row * 64 + 32 + 8 * q);
        bias_e[t] = b_e[row];
        bias_d[t] = b_d[row];
    }
    const int i_e = id >> 4;          // embed: batch row
    const int u_e = (id & 15) * 2;    // embed: unit pair
    const float4 we  = *(const float4*)(W_emb + u_e * 2);
    const float be0 = b_emb[u_e], be1 = b_emb[u_e + 1];
    const float wo0 = W_out[colb], wo1 = W_out[64 + colb];
    const float bo0 = b_out[0],   bo1 = b_out[1];

    // init h=0, stage obs
    {
        unsigned* hz = (unsigned*)&hbuf[0][0][0];
        for (int k2 = id; k2 < 1152; k2 += 256) hz[k2] = 0u;   // hi+lo of buf0
        for (int k2 = id; k2 < 640; k2 += 256) obs_l[k2] = obs[(size_t)bb * 40 + k2];
    }
    float c[4] = {0.f, 0.f, 0.f, 0.f};
    __syncthreads();

    int cur = 0;

    // ==================== encoder ====================
#pragma unroll 1
    for (int t = 0; t < OBS_LEN; ++t) {
        {   // embed: e = relu(x @ W_emb^T + b)
            const float x0 = obs_l[i_e * 40 + 2 * t];
            const float x1 = obs_l[i_e * 40 + 2 * t + 1];
            const float e0 = fmaxf(0.f, fmaf(we.x, x0, fmaf(we.y, x1, be0)));
            const float e1 = fmaxf(0.f, fmaf(we.z, x0, fmaf(we.w, x1, be1)));
            ((unsigned*)e_l)[i_e * 20 + (u_e >> 1)] =
                (unsigned)f2bf(e0) | ((unsigned)f2bf(e1) << 16);
        }
        __syncthreads();

        const unsigned short* hh = &hbuf[cur][0][0];
        const unsigned short* hl = &hbuf[cur][1][0];
        const short8v Ae = *(const short8v*)(e_l + jm * 40 + 8 * q);
        const short8v H1 = *(const short8v*)(hh + jm * 72 + 8 * q);
        const short8v H2 = *(const short8v*)(hh + jm * 72 + 32 + 8 * q);
        const short8v L1 = *(const short8v*)(hl + jm * 72 + 8 * q);
        const short8v L2 = *(const short8v*)(hl + jm * 72 + 32 + 8 * q);
        unsigned short* nh = &hbuf[cur ^ 1][0][0];
        unsigned short* nl = &hbuf[cur ^ 1][1][0];

        f32x4 gacc[4];
#pragma unroll
        for (int t4 = 0; t4 < 4; ++t4) {
            f32x4 acc = {bias_e[t4], bias_e[t4], bias_e[t4], bias_e[t4]};
            acc = MFMA(Ae, Be[0][t4], acc);
            acc = MFMA(H1, Be[1][t4], acc);
            acc = MFMA(H2, Be[2][t4], acc);
            acc = MFMA(L1, Be[1][t4], acc);   // lo-residual pass, same Whh frags
            acc = MFMA(L2, Be[2][t4], acc);
            gacc[t4] = acc;
        }
#pragma unroll
        for (int r = 0; r < 4; ++r) {
            const float ig = sigm(gacc[0][r]);
            const float fg = sigm(gacc[1][r]);
            const float gg = tanh_f(gacc[2][r]);
            const float og = sigm(gacc[3][r]);
            c[r] = fmaf(fg, c[r], ig * gg);
            const float hv = og * tanh_f(c[r]);
            const unsigned short hb = f2bf(hv);
            nh[(4 * q + r) * 72 + colb] = hb;
            nl[(4 * q + r) * 72 + colb] = f2bf(hv - bf2f(hb));
        }
        cur ^= 1;
        __syncthreads();
    }

    // ==================== cond -> decoder init ====================
    {
        {   // stage [noise | scene | 0] as bf16
            const int i2 = id >> 4, cb = (id & 15) * 6;
#pragma unroll
            for (int cc = 0; cc < 6; ++cc) {
                const int col = cb + cc;
                float v;
                if (col < 16)      v = noise[(size_t)(bb + i2) * 16 + col];
                else if (col < 80) v = scene[(size_t)(bb + i2) * 64 + (col - 16)];
                else               v = 0.f;
                ns_l[i2 * 96 + col] = f2bf(v);
            }
        }
        __syncthreads();

        const unsigned short* hh = &hbuf[cur][0][0];
        const unsigned short* hl = &hbuf[cur][1][0];
        const short8v A0 = *(const short8v*)(hh + jm * 72 + 8 * q);
        const short8v A1 = *(const short8v*)(hh + jm * 72 + 32 + 8 * q);
        const short8v L0 = *(const short8v*)(hl + jm * 72 + 8 * q);
        const short8v L1c = *(const short8v*)(hl + jm * 72 + 32 + 8 * q);
        const short8v N0 = *(const short8v*)(ns_l + jm * 96 + 8 * q);
        const short8v N1 = *(const short8v*)(ns_l + jm * 96 + 32 + 8 * q);
        const short8v N2 = *(const short8v*)(ns_l + jm * 96 + 64 + 8 * q);
        unsigned short* nh = &hbuf[cur ^ 1][0][0];
        unsigned short* nl = &hbuf[cur ^ 1][1][0];
        const short8v zfrag = {0, 0, 0, 0, 0, 0, 0, 0};

        // ---- h0 = cond @ W_h^T + b_h ----  (wave w computes n-tile w: j = colb)
        {
            short8v Bf[5];
#pragma unroll
            for (int kt = 0; kt < 4; ++kt)
                Bf[kt] = ldw8(W_h + (size_t)colb * 144 + kt * 32 + 8 * q);
            Bf[4] = (q < 2) ? ldw8(W_h + (size_t)colb * 144 + 128 + 8 * q) : zfrag;
            f32x4 ah = {b_h[colb], b_h[colb], b_h[colb], b_h[colb]};
            ah = MFMA(A0, Bf[0], ah);
            ah = MFMA(A1, Bf[1], ah);
            ah = MFMA(L0, Bf[0], ah);
            ah = MFMA(L1c, Bf[1], ah);
            ah = MFMA(N0, Bf[2], ah);
            ah = MFMA(N1, Bf[3], ah);
            ah = MFMA(N2, Bf[4], ah);
#pragma unroll
            for (int r = 0; r < 4; ++r) {
                const float hv = ah[r];
                const unsigned short hb = f2bf(hv);
                nh[(4 * q + r) * 72 + colb] = hb;
                nl[(4 * q + r) * 72 + colb] = f2bf(hv - bf2f(hb));
            }
        }
        // ---- c0 = cond @ W_c^T + b_c ----
        {
            short8v Bf[5];
#pragma unroll
            for (int kt = 0; kt < 4; ++kt)
                Bf[kt] = ldw8(W_c + (size_t)colb * 144 + kt * 32 + 8 * q);
            Bf[4] = (q < 2) ? ldw8(W_c + (size_t)colb * 144 + 128 + 8 * q) : zfrag;
            f32x4 ac = {b_c[colb], b_c[colb], b_c[colb], b_c[colb]};
            ac = MFMA(A0, Bf[0], ac);
            ac = MFMA(A1, Bf[1], ac);
            ac = MFMA(L0, Bf[0], ac);
            ac = MFMA(L1c, Bf[1], ac);
            ac = MFMA(N0, Bf[2], ac);
            ac = MFMA(N1, Bf[3], ac);
            ac = MFMA(N2, Bf[4], ac);
#pragma unroll
            for (int r = 0; r < 4; ++r) c[r] = ac[r];
        }
        cur ^= 1;
        __syncthreads();
    }

    // ==================== decoder ====================
#pragma unroll 1
    for (int t = 0; t < PRED_LEN; ++t) {
        {   // embed from y_{t-1} (or obs[:, -1] at t=0); also store y_{t-1}
            float x0, x1;
            if (t == 0) {
                x0 = obs_l[i_e * 40 + 38];
                x1 = obs_l[i_e * 40 + 39];
            } else {
                const float* yp = y_part + i_e * 8;
                x0 = yp[0] + yp[2] + yp[4] + yp[6] + bo0;
                x1 = yp[1] + yp[3] + yp[5] + yp[7] + bo1;
                if ((id & 15) == 0)
                    *(float2*)(out + (size_t)(bb + i_e) * 60 + (t - 1) * 2) =
                        make_float2(x0, x1);
            }
            const float e0 = fmaxf(0.f, fmaf(we.x, x0, fmaf(we.y, x1, be0)));
            const float e1 = fmaxf(0.f, fmaf(we.z, x0, fmaf(we.w, x1, be1)));
            ((unsigned*)e_l)[i_e * 20 + (u_e >> 1)] =
                (unsigned)f2bf(e0) | ((unsigned)f2bf(e1) << 16);
        }
        __syncthreads();

        const unsigned short* hh = &hbuf[cur][0][0];
        const unsigned short* hl = &hbuf[cur][1][0];
        const short8v Ae = *(const short8v*)(e_l + jm * 40 + 8 * q);
        const short8v H1 = *(const short8v*)(hh + jm * 72 + 8 * q);
        const short8v H2 = *(const short8v*)(hh + jm * 72 + 32 + 8 * q);
        const short8v L1 = *(const short8v*)(hl + jm * 72 + 8 * q);
        const short8v L2 = *(const short8v*)(hl + jm * 72 + 32 + 8 * q);
        unsigned short* nh = &hbuf[cur ^ 1][0][0];
        unsigned short* nl = &hbuf[cur ^ 1][1][0];

        f32x4 gacc[4];
#pragma unroll
        for (int t4 = 0; t4 < 4; ++t4) {
            f32x4 acc = {bias_d[t4], bias_d[t4], bias_d[t4], bias_d[t4]};
            acc = MFMA(Ae, Bd[0][t4], acc);
            acc = MFMA(H1, Bd[1][t4], acc);
            acc = MFMA(H2, Bd[2][t4], acc);
            acc = MFMA(L1, Bd[1][t4], acc);
            acc = MFMA(L2, Bd[2][t4], acc);
            gacc[t4] = acc;
        }
        float hr[4];
#pragma unroll
        for (int r = 0; r < 4; ++r) {
            const float ig = sigm(gacc[0][r]);
            const float fg = sigm(gacc[1][r]);
            const float gg = tanh_f(gacc[2][r]);
            const float og = sigm(gacc[3][r]);
            c[r] = fmaf(fg, c[r], ig * gg);
            const float hv = og * tanh_f(c[r]);
            hr[r] = hv;
            const unsigned short hb = f2bf(hv);
            nh[(4 * q + r) * 72 + colb] = hb;
            nl[(4 * q + r) * 72 + colb] = f2bf(hv - bf2f(hb));
        }
        // y partials: reduce over this wave's 16 j's (butterfly in low 4 lane bits)
        float p0[4], p1[4];
#pragma unroll
        for (int r = 0; r < 4; ++r) { p0[r] = hr[r] * wo0; p1[r] = hr[r] * wo1; }
#pragma unroll
        for (int m = 1; m < 16; m <<= 1) {
#pragma unroll
            for (int r = 0; r < 4; ++r) {
                p0[r] += __shfl_xor(p0[r], m, 64);
                p1[r] += __shfl_xor(p1[r], m, 64);
            }
        }
        if (jm < 2) {
#pragma unroll
            for (int r = 0; r < 4; ++r)
                y_part[(4 * q + r) * 8 + w * 2 + jm] = (jm == 0) ? p0[r] : p1[r];
        }
        cur ^= 1;
        __syncthreads();
    }

    // final y (t = PRED_LEN-1)
    if ((id & 15) == 0) {
        const float* yp = y_part + i_e * 8;
        const float x0 = yp[0] + yp[2] + yp[4] + yp[6] + bo0;
        const float x1 = yp[1] + yp[3] + yp[5] + yp[7] + bo1;
        *(float2*)(out + (size_t)(bb + i_e) * 60 + (PRED_LEN - 1) * 2) =
            make_float2(x0, x1);
    }
}

extern "C" void kernel_launch(void* const* d_in, const int* in_sizes, int n_in,
                              void* d_out, int out_size, void* d_ws, size_t ws_size,
                              hipStream_t stream) {
    (void)in_sizes; (void)n_in; (void)d_ws; (void)ws_size; (void)out_size;
    const float* obs    = (const float*)d_in[0];
    const float* noise  = (const float*)d_in[1];
    const float* scene  = (const float*)d_in[2];
    const float* W_emb  = (const float*)d_in[3];
    const float* b_emb  = (const float*)d_in[4];
    const float* Wih_e  = (const float*)d_in[5];
    const float* Whh_e  = (const float*)d_in[6];
    const float* b_e    = (const float*)d_in[7];
    const float* W_h    = (const float*)d_in[8];
    const float* b_h    = (const float*)d_in[9];
    const float* W_c    = (const float*)d_in[10];
    const float* b_c    = (const float*)d_in[11];
    const float* Wih_d  = (const float*)d_in[12];
    const float* Whh_d  = (const float*)d_in[13];
    const float* b_d    = (const float*)d_in[14];
    const float* W_out  = (const float*)d_in[15];
    const float* b_out  = (const float*)d_in[16];
    float* out = (float*)d_out;

    dim3 grid(65536 / 16), block(256);
    hipLaunchKernelGGL(traj_mfma, grid, block, 0, stream,
                       obs, noise, scene, W_emb, b_emb,
                       Wih_e, Whh_e, b_e, W_h, b_h, W_c, b_c,
                       Wih_d, Whh_d, b_d, W_out, b_out, out);
}

// Round 7
// 546.638 us; speedup vs baseline: 1.6901x; 1.6901x over previous
//
#include <hip/hip_runtime.h>
#include <hip/hip_bf16.h>
#include <cstddef>

#define OBS_LEN  20
#define PRED_LEN 30

typedef __attribute__((ext_vector_type(8))) short short8v;  // 8 bf16 (4 VGPRs)
typedef __attribute__((ext_vector_type(4))) float f32x4;

__device__ __forceinline__ float sigm(float x) {
    return __builtin_amdgcn_rcpf(1.0f + __expf(-x));
}
__device__ __forceinline__ float tanh_f(float x) {
    return fmaf(2.0f, sigm(2.0f * x), -1.0f);
}
__device__ __forceinline__ unsigned short f2bf(float x) {  // RNE
    __hip_bfloat16 h = __float2bfloat16(x);
    return __builtin_bit_cast(unsigned short, h);
}
__device__ __forceinline__ float bf2f(unsigned short u) {
    unsigned v = ((unsigned)u) << 16;
    return __builtin_bit_cast(float, v);
}
__device__ __forceinline__ short8v ldw8(const float* __restrict__ p) {
    const float4 a = *(const float4*)(p);
    const float4 b = *(const float4*)(p + 4);
    short8v r;
    r[0] = (short)f2bf(a.x); r[1] = (short)f2bf(a.y);
    r[2] = (short)f2bf(a.z); r[3] = (short)f2bf(a.w);
    r[4] = (short)f2bf(b.x); r[5] = (short)f2bf(b.y);
    r[6] = (short)f2bf(b.z); r[7] = (short)f2bf(b.w);
    return r;
}

#define MFMA(A, B, C) __builtin_amdgcn_mfma_f32_16x16x32_bf16((A), (B), (C), 0, 0, 0)

// R5 regime kept EXACTLY (launch_bounds(256,2) + ~55KB LDS -> 2 blocks/CU,
// 256-VGPR budget, VGPR~116 proven stable; R6 showed perturbing this fails).
// New: TWO independent 16-row batch tiles per block (32 rows, grid 2048) ->
// every dependency chain (MFMA gates, nonlinearity, shuffle reduce) is
// duplicated and interleaved -> ~2x ILP against the 5x latency slack.
// Weights are register-resident ONCE and shared by both tiles.
extern "C" __global__ void __launch_bounds__(256, 2)
traj_mfma(const float* __restrict__ obs,   const float* __restrict__ noise,
          const float* __restrict__ scene,
          const float* __restrict__ W_emb, const float* __restrict__ b_emb,
          const float* __restrict__ Wih_e, const float* __restrict__ Whh_e, const float* __restrict__ b_e,
          const float* __restrict__ W_h,   const float* __restrict__ b_h,
          const float* __restrict__ W_c,   const float* __restrict__ b_c,
          const float* __restrict__ Wih_d, const float* __restrict__ Whh_d, const float* __restrict__ b_d,
          const float* __restrict__ W_out, const float* __restrict__ b_out,
          float* __restrict__ out)
{
    __shared__ __align__(16) unsigned short hbuf[2][2][2][1152]; // [tile][buf][hi/lo][16*72]
    __shared__ __align__(16) unsigned short e_l[2][640];         // [tile][16*40]
    __shared__ __align__(16) unsigned short ns_l[2][1536];       // [tile][16*96]
    __shared__ __align__(16) float obs_l[1280];                  // 32 rows x 40 f32
    __shared__ __align__(16) float y_part[2][128];               // [tile][16*8]
    __shared__ float occ_pad[5400];                              // total 54880B > 163840/3 -> 2 blocks/CU

    const int id = threadIdx.x;
    if (blockIdx.x == 0xFFFFFFFFu) { occ_pad[id] = 1.0f; out[id] = occ_pad[id ^ 1]; }

    const int l    = id & 63;
    const int w    = id >> 6;        // wave = n-tile slot (gate columns)
    const int q    = l >> 4;
    const int jm   = l & 15;
    const int colb = w * 16 + jm;    // j in [0,64)
    const int bb   = blockIdx.x * 32;

    // ---------------- one-time register-resident weights (shared by both tiles) ----------------
    short8v Be[3][4], Bd[3][4];
    float bias_e[4], bias_d[4];
#pragma unroll
    for (int t = 0; t < 4; ++t) {
        const int row = t * 64 + colb;
        Be[0][t] = ldw8(Wih_e + row * 32 + 8 * q);
        Be[1][t] = ldw8(Whh_e + row * 64 + 8 * q);
        Be[2][t] = ldw8(Whh_e + row * 64 + 32 + 8 * q);
        Bd[0][t] = ldw8(Wih_d + row * 32 + 8 * q);
        Bd[1][t] = ldw8(Whh_d + row * 64 + 8 * q);
        Bd[2][t] = ldw8(Whh_d + row * 64 + 32 + 8 * q);
        bias_e[t] = b_e[row];
        bias_d[t] = b_d[row];
    }
    const int i_e = id >> 4;          // embed: row within tile
    const int u_e = (id & 15) * 2;    // embed: unit pair
    const float4 we  = *(const float4*)(W_emb + u_e * 2);
    const float be0 = b_emb[u_e], be1 = b_emb[u_e + 1];
    const float wo0 = W_out[colb], wo1 = W_out[64 + colb];
    const float bo0 = b_out[0],   bo1 = b_out[1];

    // init h=0 (all bufs, cheap), stage obs (32 rows)
    {
        unsigned* hz = (unsigned*)&hbuf[0][0][0][0];
        for (int k2 = id; k2 < 4608; k2 += 256) hz[k2] = 0u;
        for (int k2 = id; k2 < 1280; k2 += 256) obs_l[k2] = obs[(size_t)bb * 40 + k2];
    }
    float c[2][4];
#pragma unroll
    for (int p = 0; p < 2; ++p)
#pragma unroll
        for (int r = 0; r < 4; ++r) c[p][r] = 0.f;
    __syncthreads();

    int cur = 0;

    // ==================== encoder ====================
#pragma unroll 1
    for (int t = 0; t < OBS_LEN; ++t) {
#pragma unroll
        for (int p = 0; p < 2; ++p) {   // embed both tiles
            const float x0 = obs_l[(p * 16 + i_e) * 40 + 2 * t];
            const float x1 = obs_l[(p * 16 + i_e) * 40 + 2 * t + 1];
            const float e0 = fmaxf(0.f, fmaf(we.x, x0, fmaf(we.y, x1, be0)));
            const float e1 = fmaxf(0.f, fmaf(we.z, x0, fmaf(we.w, x1, be1)));
            ((unsigned*)&e_l[p][0])[i_e * 20 + (u_e >> 1)] =
                (unsigned)f2bf(e0) | ((unsigned)f2bf(e1) << 16);
        }
        __syncthreads();

        const short8v AeA = *(const short8v*)(&e_l[0][jm * 40 + 8 * q]);
        const short8v AeB = *(const short8v*)(&e_l[1][jm * 40 + 8 * q]);
        const short8v H1A = *(const short8v*)(&hbuf[0][cur][0][jm * 72 + 8 * q]);
        const short8v H1B = *(const short8v*)(&hbuf[1][cur][0][jm * 72 + 8 * q]);
        const short8v H2A = *(const short8v*)(&hbuf[0][cur][0][jm * 72 + 32 + 8 * q]);
        const short8v H2B = *(const short8v*)(&hbuf[1][cur][0][jm * 72 + 32 + 8 * q]);
        const short8v L1A = *(const short8v*)(&hbuf[0][cur][1][jm * 72 + 8 * q]);
        const short8v L1B = *(const short8v*)(&hbuf[1][cur][1][jm * 72 + 8 * q]);
        const short8v L2A = *(const short8v*)(&hbuf[0][cur][1][jm * 72 + 32 + 8 * q]);
        const short8v L2B = *(const short8v*)(&hbuf[1][cur][1][jm * 72 + 32 + 8 * q]);

        f32x4 gA[4], gB[4];
#pragma unroll
        for (int t4 = 0; t4 < 4; ++t4) {
            f32x4 a = {bias_e[t4], bias_e[t4], bias_e[t4], bias_e[t4]};
            f32x4 b = a;
            a = MFMA(AeA, Be[0][t4], a);  b = MFMA(AeB, Be[0][t4], b);
            a = MFMA(H1A, Be[1][t4], a);  b = MFMA(H1B, Be[1][t4], b);
            a = MFMA(H2A, Be[2][t4], a);  b = MFMA(H2B, Be[2][t4], b);
            a = MFMA(L1A, Be[1][t4], a);  b = MFMA(L1B, Be[1][t4], b);
            a = MFMA(L2A, Be[2][t4], a);  b = MFMA(L2B, Be[2][t4], b);
            gA[t4] = a; gB[t4] = b;
        }
#pragma unroll
        for (int p = 0; p < 2; ++p) {
            unsigned short* nh = &hbuf[p][cur ^ 1][0][0];
            unsigned short* nl = &hbuf[p][cur ^ 1][1][0];
#pragma unroll
            for (int r = 0; r < 4; ++r) {
                const f32x4* g = (p == 0) ? gA : gB;
                const float ig = sigm(g[0][r]);
                const float fg = sigm(g[1][r]);
                const float gg = tanh_f(g[2][r]);
                const float og = sigm(g[3][r]);
                c[p][r] = fmaf(fg, c[p][r], ig * gg);
                const float hv = og * tanh_f(c[p][r]);
                const unsigned short hb = f2bf(hv);
                nh[(4 * q + r) * 72 + colb] = hb;
                nl[(4 * q + r) * 72 + colb] = f2bf(hv - bf2f(hb));
            }
        }
        cur ^= 1;
        __syncthreads();
    }

    // ==================== cond -> decoder init ====================
    {
        {   // stage [noise | scene | 0] as bf16, both tiles
            const int i2 = id >> 4, cb = (id & 15) * 6;
#pragma unroll
            for (int p = 0; p < 2; ++p) {
                const int row = bb + p * 16 + i2;
#pragma unroll
                for (int cc = 0; cc < 6; ++cc) {
                    const int col = cb + cc;
                    float v;
                    if (col < 16)      v = noise[(size_t)row * 16 + col];
                    else if (col < 80) v = scene[(size_t)row * 64 + (col - 16)];
                    else               v = 0.f;
                    ns_l[p][i2 * 96 + col] = f2bf(v);
                }
            }
        }
        __syncthreads();

        const short8v A0A = *(const short8v*)(&hbuf[0][cur][0][jm * 72 + 8 * q]);
        const short8v A0B = *(const short8v*)(&hbuf[1][cur][0][jm * 72 + 8 * q]);
        const short8v A1A = *(const short8v*)(&hbuf[0][cur][0][jm * 72 + 32 + 8 * q]);
        const short8v A1B = *(const short8v*)(&hbuf[1][cur][0][jm * 72 + 32 + 8 * q]);
        const short8v L0A = *(const short8v*)(&hbuf[0][cur][1][jm * 72 + 8 * q]);
        const short8v L0B = *(const short8v*)(&hbuf[1][cur][1][jm * 72 + 8 * q]);
        const short8v L1A = *(const short8v*)(&hbuf[0][cur][1][jm * 72 + 32 + 8 * q]);
        const short8v L1B = *(const short8v*)(&hbuf[1][cur][1][jm * 72 + 32 + 8 * q]);
        const short8v N0A = *(const short8v*)(&ns_l[0][jm * 96 + 8 * q]);
        const short8v N0B = *(const short8v*)(&ns_l[1][jm * 96 + 8 * q]);
        const short8v N1A = *(const short8v*)(&ns_l[0][jm * 96 + 32 + 8 * q]);
        const short8v N1B = *(const short8v*)(&ns_l[1][jm * 96 + 32 + 8 * q]);
        const short8v N2A = *(const short8v*)(&ns_l[0][jm * 96 + 64 + 8 * q]);
        const short8v N2B = *(const short8v*)(&ns_l[1][jm * 96 + 64 + 8 * q]);
        const short8v zfrag = {0, 0, 0, 0, 0, 0, 0, 0};

        // ---- h0 ----
        {
            short8v Bf[5];
#pragma unroll
            for (int kt = 0; kt < 4; ++kt)
                Bf[kt] = ldw8(W_h + (size_t)colb * 144 + kt * 32 + 8 * q);
            Bf[4] = (q < 2) ? ldw8(W_h + (size_t)colb * 144 + 128 + 8 * q) : zfrag;
            f32x4 ahA = {b_h[colb], b_h[colb], b_h[colb], b_h[colb]};
            f32x4 ahB = ahA;
            ahA = MFMA(A0A, Bf[0], ahA);  ahB = MFMA(A0B, Bf[0], ahB);
            ahA = MFMA(A1A, Bf[1], ahA);  ahB = MFMA(A1B, Bf[1], ahB);
            ahA = MFMA(L0A, Bf[0], ahA);  ahB = MFMA(L0B, Bf[0], ahB);
            ahA = MFMA(L1A, Bf[1], ahA);  ahB = MFMA(L1B, Bf[1], ahB);
            ahA = MFMA(N0A, Bf[2], ahA);  ahB = MFMA(N0B, Bf[2], ahB);
            ahA = MFMA(N1A, Bf[3], ahA);  ahB = MFMA(N1B, Bf[3], ahB);
            ahA = MFMA(N2A, Bf[4], ahA);  ahB = MFMA(N2B, Bf[4], ahB);
#pragma unroll
            for (int p = 0; p < 2; ++p) {
                unsigned short* nh = &hbuf[p][cur ^ 1][0][0];
                unsigned short* nl = &hbuf[p][cur ^ 1][1][0];
#pragma unroll
                for (int r = 0; r < 4; ++r) {
                    const float hv = (p == 0) ? ahA[r] : ahB[r];
                    const unsigned short hb = f2bf(hv);
                    nh[(4 * q + r) * 72 + colb] = hb;
                    nl[(4 * q + r) * 72 + colb] = f2bf(hv - bf2f(hb));
                }
            }
        }
        // ---- c0 ----
        {
            short8v Bf[5];
#pragma unroll
            for (int kt = 0; kt < 4; ++kt)
                Bf[kt] = ldw8(W_c + (size_t)colb * 144 + kt * 32 + 8 * q);
            Bf[4] = (q < 2) ? ldw8(W_c + (size_t)colb * 144 + 128 + 8 * q) : zfrag;
            f32x4 acA = {b_c[colb], b_c[colb], b_c[colb], b_c[colb]};
            f32x4 acB = acA;
            acA = MFMA(A0A, Bf[0], acA);  acB = MFMA(A0B, Bf[0], acB);
            acA = MFMA(A1A, Bf[1], acA);  acB = MFMA(A1B, Bf[1], acB);
            acA = MFMA(L0A, Bf[0], acA);  acB = MFMA(L0B, Bf[0], acB);
            acA = MFMA(L1A, Bf[1], acA);  acB = MFMA(L1B, Bf[1], acB);
            acA = MFMA(N0A, Bf[2], acA);  acB = MFMA(N0B, Bf[2], acB);
            acA = MFMA(N1A, Bf[3], acA);  acB = MFMA(N1B, Bf[3], acB);
            acA = MFMA(N2A, Bf[4], acA);  acB = MFMA(N2B, Bf[4], acB);
#pragma unroll
            for (int r = 0; r < 4; ++r) { c[0][r] = acA[r]; c[1][r] = acB[r]; }
        }
        cur ^= 1;
        __syncthreads();
    }

    // ==================== decoder ====================
#pragma unroll 1
    for (int t = 0; t < PRED_LEN; ++t) {
#pragma unroll
        for (int p = 0; p < 2; ++p) {   // embed from y_{t-1}; store y_{t-1}
            float x0, x1;
            if (t == 0) {
                x0 = obs_l[(p * 16 + i_e) * 40 + 38];
                x1 = obs_l[(p * 16 + i_e) * 40 + 39];
            } else {
                const float* yp = &y_part[p][i_e * 8];
                x0 = yp[0] + yp[2] + yp[4] + yp[6] + bo0;
                x1 = yp[1] + yp[3] + yp[5] + yp[7] + bo1;
                if ((id & 15) == 0)
                    *(float2*)(out + (size_t)(bb + p * 16 + i_e) * 60 + (t - 1) * 2) =
                        make_float2(x0, x1);
            }
            const float e0 = fmaxf(0.f, fmaf(we.x, x0, fmaf(we.y, x1, be0)));
            const float e1 = fmaxf(0.f, fmaf(we.z, x0, fmaf(we.w, x1, be1)));
            ((unsigned*)&e_l[p][0])[i_e * 20 + (u_e >> 1)] =
                (unsigned)f2bf(e0) | ((unsigned)f2bf(e1) << 16);
        }
        __syncthreads();

        const short8v AeA = *(const short8v*)(&e_l[0][jm * 40 + 8 * q]);
        const short8v AeB = *(const short8v*)(&e_l[1][jm * 40 + 8 * q]);
        const short8v H1A = *(const short8v*)(&hbuf[0][cur][0][jm * 72 + 8 * q]);
        const short8v H1B = *(const short8v*)(&hbuf[1][cur][0][jm * 72 + 8 * q]);
        const short8v H2A = *(const short8v*)(&hbuf[0][cur][0][jm * 72 + 32 + 8 * q]);
        const short8v H2B = *(const short8v*)(&hbuf[1][cur][0][jm * 72 + 32 + 8 * q]);
        const short8v L1A = *(const short8v*)(&hbuf[0][cur][1][jm * 72 + 8 * q]);
        const short8v L1B = *(const short8v*)(&hbuf[1][cur][1][jm * 72 + 8 * q]);
        const short8v L2A = *(const short8v*)(&hbuf[0][cur][1][jm * 72 + 32 + 8 * q]);
        const short8v L2B = *(const short8v*)(&hbuf[1][cur][1][jm * 72 + 32 + 8 * q]);

        f32x4 gA[4], gB[4];
#pragma unroll
        for (int t4 = 0; t4 < 4; ++t4) {
            f32x4 a = {bias_d[t4], bias_d[t4], bias_d[t4], bias_d[t4]};
            f32x4 b = a;
            a = MFMA(AeA, Bd[0][t4], a);  b = MFMA(AeB, Bd[0][t4], b);
            a = MFMA(H1A, Bd[1][t4], a);  b = MFMA(H1B, Bd[1][t4], b);
            a = MFMA(H2A, Bd[2][t4], a);  b = MFMA(H2B, Bd[2][t4], b);
            a = MFMA(L1A, Bd[1][t4], a);  b = MFMA(L1B, Bd[1][t4], b);
            a = MFMA(L2A, Bd[2][t4], a);  b = MFMA(L2B, Bd[2][t4], b);
            gA[t4] = a; gB[t4] = b;
        }
        float hr[2][4];
#pragma unroll
        for (int p = 0; p < 2; ++p) {
            unsigned short* nh = &hbuf[p][cur ^ 1][0][0];
            unsigned short* nl = &hbuf[p][cur ^ 1][1][0];
#pragma unroll
            for (int r = 0; r < 4; ++r) {
                const f32x4* g = (p == 0) ? gA : gB;
                const float ig = sigm(g[0][r]);
                const float fg = sigm(g[1][r]);
                const float gg = tanh_f(g[2][r]);
                const float og = sigm(g[3][r]);
                c[p][r] = fmaf(fg, c[p][r], ig * gg);
                const float hv = og * tanh_f(c[p][r]);
                hr[p][r] = hv;
                const unsigned short hb = f2bf(hv);
                nh[(4 * q + r) * 72 + colb] = hb;
                nl[(4 * q + r) * 72 + colb] = f2bf(hv - bf2f(hb));
            }
        }
        // y partials: 16 independent shuffle chains (2 tiles x 4 r x 2 ch)
        float p0[2][4], p1[2][4];
#pragma unroll
        for (int p = 0; p < 2; ++p)
#pragma unroll
            for (int r = 0; r < 4; ++r) {
                p0[p][r] = hr[p][r] * wo0;
                p1[p][r] = hr[p][r] * wo1;
            }
#pragma unroll
        for (int m = 1; m < 16; m <<= 1) {
#pragma unroll
            for (int p = 0; p < 2; ++p)
#pragma unroll
                for (int r = 0; r < 4; ++r) {
                    p0[p][r] += __shfl_xor(p0[p][r], m, 64);
                    p1[p][r] += __shfl_xor(p1[p][r], m, 64);
                }
        }
        if (jm < 2) {
#pragma unroll
            for (int p = 0; p < 2; ++p)
#pragma unroll
                for (int r = 0; r < 4; ++r)
                    y_part[p][(4 * q + r) * 8 + w * 2 + jm] =
                        (jm == 0) ? p0[p][r] : p1[p][r];
        }
        cur ^= 1;
        __syncthreads();
    }

    // final y (t = PRED_LEN-1)
    if ((id & 15) == 0) {
#pragma unroll
        for (int p = 0; p < 2; ++p) {
            const float* yp = &y_part[p][i_e * 8];
            const float x0 = yp[0] + yp[2] + yp[4] + yp[6] + bo0;
            const float x1 = yp[1] + yp[3] + yp[5] + yp[7] + bo1;
            *(float2*)(out + (size_t)(bb + p * 16 + i_e) * 60 + (PRED_LEN - 1) * 2) =
                make_float2(x0, x1);
        }
    }
}

extern "C" void kernel_launch(void* const* d_in, const int* in_sizes, int n_in,
                              void* d_out, int out_size, void* d_ws, size_t ws_size,
                              hipStream_t stream) {
    (void)in_sizes; (void)n_in; (void)d_ws; (void)ws_size; (void)out_size;
    const float* obs    = (const float*)d_in[0];
    const float* noise  = (const float*)d_in[1];
    const float* scene  = (const float*)d_in[2];
    const float* W_emb  = (const float*)d_in[3];
    const float* b_emb  = (const float*)d_in[4];
    const float* Wih_e  = (const float*)d_in[5];
    const float* Whh_e  = (const float*)d_in[6];
    const float* b_e    = (const float*)d_in[7];
    const float* W_h    = (const float*)d_in[8];
    const float* b_h    = (const float*)d_in[9];
    const float* W_c    = (const float*)d_in[10];
    const float* b_c    = (const float*)d_in[11];
    const float* Wih_d  = (const float*)d_in[12];
    const float* Whh_d  = (const float*)d_in[13];
    const float* b_d    = (const float*)d_in[14];
    const float* W_out  = (const float*)d_in[15];
    const float* b_out  = (const float*)d_in[16];
    float* out = (float*)d_out;

    dim3 grid(65536 / 32), block(256);
    hipLaunchKernelGGL(traj_mfma, grid, block, 0, stream,
                       obs, noise, scene, W_emb, b_emb,
                       Wih_e, Whh_e, b_e, W_h, b_h, W_c, b_c,
                       Wih_d, Whh_d, b_d, W_out, b_out, out);
}

// Round 8
// 448.894 us; speedup vs baseline: 2.0581x; 1.2177x over previous
//
#include <hip/hip_runtime.h>
#include <cstddef>

#define OBS_LEN  20
#define PRED_LEN 30

typedef __attribute__((ext_vector_type(8))) short short8v;  // 8 bf16 (4 VGPRs)
typedef __attribute__((ext_vector_type(4))) float f32x4;

__device__ __forceinline__ float sigm(float x) {
    return __builtin_amdgcn_rcpf(1.0f + __expf(-x));
}
__device__ __forceinline__ float tanh_f(float x) {
    return fmaf(2.0f, sigm(2.0f * x), -1.0f);
}
// branchless RNE f32->bf16 (4 int ops, no libcall)
__device__ __forceinline__ unsigned short f2bf_rne(float x) {
    const unsigned u = __builtin_bit_cast(unsigned, x);
    return (unsigned short)((u + 0x7FFFu + ((u >> 16) & 1u)) >> 16);
}
// weight-row load -> bf16x8 fragment (RNE; one-time cost)
__device__ __forceinline__ short8v ldw8(const float* __restrict__ p) {
    const float4 a = *(const float4*)(p);
    const float4 b = *(const float4*)(p + 4);
    uint4 w;
    w.x = (unsigned)f2bf_rne(a.x) | ((unsigned)f2bf_rne(a.y) << 16);
    w.y = (unsigned)f2bf_rne(a.z) | ((unsigned)f2bf_rne(a.w) << 16);
    w.z = (unsigned)f2bf_rne(b.x) | ((unsigned)f2bf_rne(b.y) << 16);
    w.w = (unsigned)f2bf_rne(b.z) | ((unsigned)f2bf_rne(b.w) << 16);
    return __builtin_bit_cast(short8v, w);
}
// per-lane embed: 8 units (rows 8q..8q+7) of one batch row -> A-fragment
__device__ __forceinline__ short8v embed8(float x0, float x1,
        const float wE0[8], const float wE1[8], const float bE[8]) {
    unsigned short s[8];
#pragma unroll
    for (int j = 0; j < 8; ++j) {
        const float e = fmaxf(0.f, fmaf(wE0[j], x0, fmaf(wE1[j], x1, bE[j])));
        s[j] = f2bf_rne(e);
    }
    uint4 w;
    w.x = (unsigned)s[0] | ((unsigned)s[1] << 16);
    w.y = (unsigned)s[2] | ((unsigned)s[3] << 16);
    w.z = (unsigned)s[4] | ((unsigned)s[5] << 16);
    w.w = (unsigned)s[6] | ((unsigned)s[7] << 16);
    return __builtin_bit_cast(short8v, w);
}

#define MFMA(A, B, C) __builtin_amdgcn_mfma_f32_16x16x32_bf16((A), (B), (C), 0, 0, 0)

// Stable regime (R5/R7): launch_bounds(256,2) + ~56KB LDS -> 2 blocks/CU ->
// regalloc gets the full 256-VGPR budget. 2 tiles x 16 rows per block.
// New vs R7: output head via MFMA (W_out as B-frag, reuses the H/L frags),
// embed computed in-register into A-frags (e_l LDS + 1 barrier/enc-step gone),
// truncation-based h hi/lo split (lo captures trunc error exactly).
extern "C" __global__ void __launch_bounds__(256, 2)
traj_mfma(const float* __restrict__ obs,   const float* __restrict__ noise,
          const float* __restrict__ scene,
          const float* __restrict__ W_emb, const float* __restrict__ b_emb,
          const float* __restrict__ Wih_e, const float* __restrict__ Whh_e, const float* __restrict__ b_e,
          const float* __restrict__ W_h,   const float* __restrict__ b_h,
          const float* __restrict__ W_c,   const float* __restrict__ b_c,
          const float* __restrict__ Wih_d, const float* __restrict__ Whh_d, const float* __restrict__ b_d,
          const float* __restrict__ W_out, const float* __restrict__ b_out,
          float* __restrict__ out)
{
    __shared__ __align__(16) unsigned short hbuf[2][2][2][1152]; // [tile][buf][hi/lo] 16x72
    __shared__ __align__(16) unsigned short ns_l[2][1536];       // [tile][16*96]
    __shared__ __align__(16) float obs_l[1280];                  // 32 rows x 40 f32
    __shared__ __align__(16) float y_lds[2][16][2];              // y broadcast
    __shared__ float occ_pad[6600];                              // -> 56.3KB total: 2 blocks/CU

    const int id = threadIdx.x;
    if (blockIdx.x == 0xFFFFFFFFu) { occ_pad[id] = 1.0f; out[id] = occ_pad[id ^ 1]; }

    const int l    = id & 63;
    const int w    = id >> 6;        // wave = gate-column slice
    const int q    = l >> 4;
    const int jm   = l & 15;
    const int colb = w * 16 + jm;    // hidden j in [0,64)
    const int bb   = blockIdx.x * 32;

    // ---------------- one-time register-resident weights ----------------
    short8v Be[3][4], Bd[3][4];
    float bias_e[4], bias_d[4];
#pragma unroll
    for (int t = 0; t < 4; ++t) {
        const int row = t * 64 + colb;
        Be[0][t] = ldw8(Wih_e + row * 32 + 8 * q);
        Be[1][t] = ldw8(Whh_e + row * 64 + 8 * q);
        Be[2][t] = ldw8(Whh_e + row * 64 + 32 + 8 * q);
        Bd[0][t] = ldw8(Wih_d + row * 32 + 8 * q);
        Bd[1][t] = ldw8(Whh_d + row * 64 + 8 * q);
        Bd[2][t] = ldw8(Whh_d + row * 64 + 32 + 8 * q);
        bias_e[t] = b_e[row];
        bias_d[t] = b_d[row];
    }
    // W_out as B-fragment: col = jm (0/1 valid), k = 8q..
    short8v Bo0, Bo1;
    {
        const short8v z = {0, 0, 0, 0, 0, 0, 0, 0};
        if (jm < 2) {
            Bo0 = ldw8(W_out + jm * 64 + 8 * q);
            Bo1 = ldw8(W_out + jm * 64 + 32 + 8 * q);
        } else { Bo0 = z; Bo1 = z; }
    }
    // per-lane embed weights: units 8q..8q+7
    float wE0[8], wE1[8], bE[8];
#pragma unroll
    for (int j = 0; j < 8; ++j) {
        wE0[j] = W_emb[(8 * q + j) * 2];
        wE1[j] = W_emb[(8 * q + j) * 2 + 1];
        bE[j]  = b_emb[8 * q + j];
    }
    const float bo0 = b_out[0], bo1 = b_out[1];

    // init h=0, stage obs (32 rows)
    {
        unsigned* hz = (unsigned*)&hbuf[0][0][0][0];
        for (int k2 = id; k2 < 4608; k2 += 256) hz[k2] = 0u;
        for (int k2 = id; k2 < 1280; k2 += 256) obs_l[k2] = obs[(size_t)bb * 40 + k2];
    }
    float c[2][4];
#pragma unroll
    for (int p = 0; p < 2; ++p)
#pragma unroll
        for (int r = 0; r < 4; ++r) c[p][r] = 0.f;
    __syncthreads();

    int cur = 0;

    // store hi/lo via truncation (lo captures the exact residual)
#define H_STORE(nh, nl, hv, rr)                                              \
    {                                                                        \
        const unsigned uh = __builtin_bit_cast(unsigned, (hv));              \
        (nh)[(4 * q + (rr)) * 72 + colb] = (unsigned short)(uh >> 16);       \
        const float lo = (hv) - __builtin_bit_cast(float, uh & 0xFFFF0000u); \
        (nl)[(4 * q + (rr)) * 72 + colb] =                                   \
            (unsigned short)(__builtin_bit_cast(unsigned, lo) >> 16);        \
    }

    // ==================== encoder (1 barrier/step) ====================
#pragma unroll 1
    for (int t = 0; t < OBS_LEN; ++t) {
        const short8v AeA = embed8(obs_l[jm * 40 + 2 * t], obs_l[jm * 40 + 2 * t + 1],
                                   wE0, wE1, bE);
        const short8v AeB = embed8(obs_l[(16 + jm) * 40 + 2 * t], obs_l[(16 + jm) * 40 + 2 * t + 1],
                                   wE0, wE1, bE);
        const short8v H1A = *(const short8v*)(&hbuf[0][cur][0][jm * 72 + 8 * q]);
        const short8v H2A = *(const short8v*)(&hbuf[0][cur][0][jm * 72 + 32 + 8 * q]);
        const short8v L1A = *(const short8v*)(&hbuf[0][cur][1][jm * 72 + 8 * q]);
        const short8v L2A = *(const short8v*)(&hbuf[0][cur][1][jm * 72 + 32 + 8 * q]);
        const short8v H1B = *(const short8v*)(&hbuf[1][cur][0][jm * 72 + 8 * q]);
        const short8v H2B = *(const short8v*)(&hbuf[1][cur][0][jm * 72 + 32 + 8 * q]);
        const short8v L1B = *(const short8v*)(&hbuf[1][cur][1][jm * 72 + 8 * q]);
        const short8v L2B = *(const short8v*)(&hbuf[1][cur][1][jm * 72 + 32 + 8 * q]);

        f32x4 gA[4], gB[4];
#pragma unroll
        for (int t4 = 0; t4 < 4; ++t4) {
            f32x4 a = {bias_e[t4], bias_e[t4], bias_e[t4], bias_e[t4]};
            f32x4 b = a;
            a = MFMA(AeA, Be[0][t4], a);  b = MFMA(AeB, Be[0][t4], b);
            a = MFMA(H1A, Be[1][t4], a);  b = MFMA(H1B, Be[1][t4], b);
            a = MFMA(H2A, Be[2][t4], a);  b = MFMA(H2B, Be[2][t4], b);
            a = MFMA(L1A, Be[1][t4], a);  b = MFMA(L1B, Be[1][t4], b);
            a = MFMA(L2A, Be[2][t4], a);  b = MFMA(L2B, Be[2][t4], b);
            gA[t4] = a; gB[t4] = b;
        }
#pragma unroll
        for (int p = 0; p < 2; ++p) {
            unsigned short* nh = &hbuf[p][cur ^ 1][0][0];
            unsigned short* nl = &hbuf[p][cur ^ 1][1][0];
#pragma unroll
            for (int r = 0; r < 4; ++r) {
                const f32x4* g = (p == 0) ? gA : gB;
                const float ig = sigm(g[0][r]);
                const float fg = sigm(g[1][r]);
                const float gg = tanh_f(g[2][r]);
                const float og = sigm(g[3][r]);
                c[p][r] = fmaf(fg, c[p][r], ig * gg);
                const float hv = og * tanh_f(c[p][r]);
                H_STORE(nh, nl, hv, r);
            }
        }
        __syncthreads();
        cur ^= 1;
    }

    // ==================== cond -> decoder init ====================
    {
        {   // stage [noise | scene | 0] as bf16
            const int i2 = id >> 4, cb = (id & 15) * 6;
#pragma unroll
            for (int p = 0; p < 2; ++p) {
                const int row = bb + p * 16 + i2;
#pragma unroll
                for (int cc = 0; cc < 6; ++cc) {
                    const int col = cb + cc;
                    float v;
                    if (col < 16)      v = noise[(size_t)row * 16 + col];
                    else if (col < 80) v = scene[(size_t)row * 64 + (col - 16)];
                    else               v = 0.f;
                    ns_l[p][i2 * 96 + col] = f2bf_rne(v);
                }
            }
        }
        __syncthreads();

        const short8v A0A = *(const short8v*)(&hbuf[0][cur][0][jm * 72 + 8 * q]);
        const short8v A1A = *(const short8v*)(&hbuf[0][cur][0][jm * 72 + 32 + 8 * q]);
        const short8v L0A = *(const short8v*)(&hbuf[0][cur][1][jm * 72 + 8 * q]);
        const short8v L1A = *(const short8v*)(&hbuf[0][cur][1][jm * 72 + 32 + 8 * q]);
        const short8v A0B = *(const short8v*)(&hbuf[1][cur][0][jm * 72 + 8 * q]);
        const short8v A1B = *(const short8v*)(&hbuf[1][cur][0][jm * 72 + 32 + 8 * q]);
        const short8v L0B = *(const short8v*)(&hbuf[1][cur][1][jm * 72 + 8 * q]);
        const short8v L1B = *(const short8v*)(&hbuf[1][cur][1][jm * 72 + 32 + 8 * q]);
        const short8v N0A = *(const short8v*)(&ns_l[0][jm * 96 + 8 * q]);
        const short8v N1A = *(const short8v*)(&ns_l[0][jm * 96 + 32 + 8 * q]);
        const short8v N2A = *(const short8v*)(&ns_l[0][jm * 96 + 64 + 8 * q]);
        const short8v N0B = *(const short8v*)(&ns_l[1][jm * 96 + 8 * q]);
        const short8v N1B = *(const short8v*)(&ns_l[1][jm * 96 + 32 + 8 * q]);
        const short8v N2B = *(const short8v*)(&ns_l[1][jm * 96 + 64 + 8 * q]);
        const short8v zfrag = {0, 0, 0, 0, 0, 0, 0, 0};

        {   // h0
            short8v Bf[5];
#pragma unroll
            for (int kt = 0; kt < 4; ++kt)
                Bf[kt] = ldw8(W_h + (size_t)colb * 144 + kt * 32 + 8 * q);
            Bf[4] = (q < 2) ? ldw8(W_h + (size_t)colb * 144 + 128 + 8 * q) : zfrag;
            f32x4 ahA = {b_h[colb], b_h[colb], b_h[colb], b_h[colb]};
            f32x4 ahB = ahA;
            ahA = MFMA(A0A, Bf[0], ahA);  ahB = MFMA(A0B, Bf[0], ahB);
            ahA = MFMA(A1A, Bf[1], ahA);  ahB = MFMA(A1B, Bf[1], ahB);
            ahA = MFMA(L0A, Bf[0], ahA);  ahB = MFMA(L0B, Bf[0], ahB);
            ahA = MFMA(L1A, Bf[1], ahA);  ahB = MFMA(L1B, Bf[1], ahB);
            ahA = MFMA(N0A, Bf[2], ahA);  ahB = MFMA(N0B, Bf[2], ahB);
            ahA = MFMA(N1A, Bf[3], ahA);  ahB = MFMA(N1B, Bf[3], ahB);
            ahA = MFMA(N2A, Bf[4], ahA);  ahB = MFMA(N2B, Bf[4], ahB);
#pragma unroll
            for (int p = 0; p < 2; ++p) {
                unsigned short* nh = &hbuf[p][cur ^ 1][0][0];
                unsigned short* nl = &hbuf[p][cur ^ 1][1][0];
#pragma unroll
                for (int r = 0; r < 4; ++r) {
                    const float hv = (p == 0) ? ahA[r] : ahB[r];
                    H_STORE(nh, nl, hv, r);
                }
            }
        }
        {   // c0
            short8v Bf[5];
#pragma unroll
            for (int kt = 0; kt < 4; ++kt)
                Bf[kt] = ldw8(W_c + (size_t)colb * 144 + kt * 32 + 8 * q);
            Bf[4] = (q < 2) ? ldw8(W_c + (size_t)colb * 144 + 128 + 8 * q) : zfrag;
            f32x4 acA = {b_c[colb], b_c[colb], b_c[colb], b_c[colb]};
            f32x4 acB = acA;
            acA = MFMA(A0A, Bf[0], acA);  acB = MFMA(A0B, Bf[0], acB);
            acA = MFMA(A1A, Bf[1], acA);  acB = MFMA(A1B, Bf[1], acB);
            acA = MFMA(L0A, Bf[0], acA);  acB = MFMA(L0B, Bf[0], acB);
            acA = MFMA(L1A, Bf[1], acA);  acB = MFMA(L1B, Bf[1], acB);
            acA = MFMA(N0A, Bf[2], acA);  acB = MFMA(N0B, Bf[2], acB);
            acA = MFMA(N1A, Bf[3], acA);  acB = MFMA(N1B, Bf[3], acB);
            acA = MFMA(N2A, Bf[4], acA);  acB = MFMA(N2B, Bf[4], acB);
#pragma unroll
            for (int r = 0; r < 4; ++r) { c[0][r] = acA[r]; c[1][r] = acB[r]; }
        }
        __syncthreads();
        cur ^= 1;
    }

    // ==================== decoder ====================
#pragma unroll 1
    for (int t = 0; t < PRED_LEN; ++t) {
        const short8v H1A = *(const short8v*)(&hbuf[0][cur][0][jm * 72 + 8 * q]);
        const short8v H2A = *(const short8v*)(&hbuf[0][cur][0][jm * 72 + 32 + 8 * q]);
        const short8v L1A = *(const short8v*)(&hbuf[0][cur][1][jm * 72 + 8 * q]);
        const short8v L2A = *(const short8v*)(&hbuf[0][cur][1][jm * 72 + 32 + 8 * q]);
        const short8v H1B = *(const short8v*)(&hbuf[1][cur][0][jm * 72 + 8 * q]);
        const short8v H2B = *(const short8v*)(&hbuf[1][cur][0][jm * 72 + 32 + 8 * q]);
        const short8v L1B = *(const short8v*)(&hbuf[1][cur][1][jm * 72 + 8 * q]);
        const short8v L2B = *(const short8v*)(&hbuf[1][cur][1][jm * 72 + 32 + 8 * q]);

        if (t > 0) {   // y_{t-1} = h_t @ W_out^T via MFMA (reuses the frags above)
            f32x4 yA = {0.f, 0.f, 0.f, 0.f}, yB = {0.f, 0.f, 0.f, 0.f};
            yA = MFMA(H1A, Bo0, yA);  yB = MFMA(H1B, Bo0, yB);
            yA = MFMA(H2A, Bo1, yA);  yB = MFMA(H2B, Bo1, yB);
            yA = MFMA(L1A, Bo0, yA);  yB = MFMA(L1B, Bo0, yB);
            yA = MFMA(L2A, Bo1, yA);  yB = MFMA(L2B, Bo1, yB);
            if (w == 0 && jm < 2) {
#pragma unroll
                for (int r = 0; r < 4; ++r) y_lds[0][4 * q + r][jm] = yA[r];
            }
            if (w == 1 && jm < 2) {
#pragma unroll
                for (int r = 0; r < 4; ++r) y_lds[1][4 * q + r][jm] = yB[r];
            }
            __syncthreads();   // barrier A: y_lds visible (replaces e-staging barrier)
        }

        float xA0, xA1, xB0, xB1;
        if (t == 0) {
            xA0 = obs_l[jm * 40 + 38];        xA1 = obs_l[jm * 40 + 39];
            xB0 = obs_l[(16 + jm) * 40 + 38]; xB1 = obs_l[(16 + jm) * 40 + 39];
        } else {
            xA0 = y_lds[0][jm][0] + bo0;  xA1 = y_lds[0][jm][1] + bo1;
            xB0 = y_lds[1][jm][0] + bo0;  xB1 = y_lds[1][jm][1] + bo1;
            if (id < 16)
                *(float2*)(out + (size_t)(bb + id) * 60 + (t - 1) * 2) = make_float2(xA0, xA1);
            else if (id >= 64 && id < 80)
                *(float2*)(out + (size_t)(bb + 16 + (id - 64)) * 60 + (t - 1) * 2) = make_float2(xB0, xB1);
        }
        const short8v AeA = embed8(xA0, xA1, wE0, wE1, bE);
        const short8v AeB = embed8(xB0, xB1, wE0, wE1, bE);

        f32x4 gA[4], gB[4];
#pragma unroll
        for (int t4 = 0; t4 < 4; ++t4) {
            f32x4 a = {bias_d[t4], bias_d[t4], bias_d[t4], bias_d[t4]};
            f32x4 b = a;
            a = MFMA(AeA, Bd[0][t4], a);  b = MFMA(AeB, Bd[0][t4], b);
            a = MFMA(H1A, Bd[1][t4], a);  b = MFMA(H1B, Bd[1][t4], b);
            a = MFMA(H2A, Bd[2][t4], a);  b = MFMA(H2B, Bd[2][t4], b);
            a = MFMA(L1A, Bd[1][t4], a);  b = MFMA(L1B, Bd[1][t4], b);
            a = MFMA(L2A, Bd[2][t4], a);  b = MFMA(L2B, Bd[2][t4], b);
            gA[t4] = a; gB[t4] = b;
        }
#pragma unroll
        for (int p = 0; p < 2; ++p) {
            unsigned short* nh = &hbuf[p][cur ^ 1][0][0];
            unsigned short* nl = &hbuf[p][cur ^ 1][1][0];
#pragma unroll
            for (int r = 0; r < 4; ++r) {
                const f32x4* g = (p == 0) ? gA : gB;
                const float ig = sigm(g[0][r]);
                const float fg = sigm(g[1][r]);
                const float gg = tanh_f(g[2][r]);
                const float og = sigm(g[3][r]);
                c[p][r] = fmaf(fg, c[p][r], ig * gg);
                const float hv = og * tanh_f(c[p][r]);
                H_STORE(nh, nl, hv, r);
            }
        }
        __syncthreads();   // barrier B: hbuf[cur^1] visible
        cur ^= 1;
    }

    // ==================== final y (pred 29) from h_30 ====================
    {
        const short8v H1A = *(const short8v*)(&hbuf[0][cur][0][jm * 72 + 8 * q]);
        const short8v H2A = *(const short8v*)(&hbuf[0][cur][0][jm * 72 + 32 + 8 * q]);
        const short8v L1A = *(const short8v*)(&hbuf[0][cur][1][jm * 72 + 8 * q]);
        const short8v L2A = *(const short8v*)(&hbuf[0][cur][1][jm * 72 + 32 + 8 * q]);
        const short8v H1B = *(const short8v*)(&hbuf[1][cur][0][jm * 72 + 8 * q]);
        const short8v H2B = *(const short8v*)(&hbuf[1][cur][0][jm * 72 + 32 + 8 * q]);
        const short8v L1B = *(const short8v*)(&hbuf[1][cur][1][jm * 72 + 8 * q]);
        const short8v L2B = *(const short8v*)(&hbuf[1][cur][1][jm * 72 + 32 + 8 * q]);
        f32x4 yA = {0.f, 0.f, 0.f, 0.f}, yB = {0.f, 0.f, 0.f, 0.f};
        yA = MFMA(H1A, Bo0, yA);  yB = MFMA(H1B, Bo0, yB);
        yA = MFMA(H2A, Bo1, yA);  yB = MFMA(H2B, Bo1, yB);
        yA = MFMA(L1A, Bo0, yA);  yB = MFMA(L1B, Bo0, yB);
        yA = MFMA(L2A, Bo1, yA);  yB = MFMA(L2B, Bo1, yB);
        if (w == 0 && jm < 2) {
#pragma unroll
            for (int r = 0; r < 4; ++r) y_lds[0][4 * q + r][jm] = yA[r];
        }
        if (w == 1 && jm < 2) {
#pragma unroll
            for (int r = 0; r < 4; ++r) y_lds[1][4 * q + r][jm] = yB[r];
        }
        __syncthreads();
        if (id < 16)
            *(float2*)(out + (size_t)(bb + id) * 60 + (PRED_LEN - 1) * 2) =
                make_float2(y_lds[0][id][0] + bo0, y_lds[0][id][1] + bo1);
        else if (id >= 64 && id < 80)
            *(float2*)(out + (size_t)(bb + 16 + (id - 64)) * 60 + (PRED_LEN - 1) * 2) =
                make_float2(y_lds[1][id - 64][0] + bo0, y_lds[1][id - 64][1] + bo1);
    }
#undef H_STORE
}

extern "C" void kernel_launch(void* const* d_in, const int* in_sizes, int n_in,
                              void* d_out, int out_size, void* d_ws, size_t ws_size,
                              hipStream_t stream) {
    (void)in_sizes; (void)n_in; (void)d_ws; (void)ws_size; (void)out_size;
    const float* obs    = (const float*)d_in[0];
    const float* noise  = (const float*)d_in[1];
    const float* scene  = (const float*)d_in[2];
    const float* W_emb  = (const float*)d_in[3];
    const float* b_emb  = (const float*)d_in[4];
    const float* Wih_e  = (const float*)d_in[5];
    const float* Whh_e  = (const float*)d_in[6];
    const float* b_e    = (const float*)d_in[7];
    const float* W_h    = (const float*)d_in[8];
    const float* b_h    = (const float*)d_in[9];
    const float* W_c    = (const float*)d_in[10];
    const float* b_c    = (const float*)d_in[11];
    const float* Wih_d  = (const float*)d_in[12];
    const float* Whh_d  = (const float*)d_in[13];
    const float* b_d    = (const float*)d_in[14];
    const float* W_out  = (const float*)d_in[15];
    const float* b_out  = (const float*)d_in[16];
    float* out = (float*)d_out;

    dim3 grid(65536 / 32), block(256);
    hipLaunchKernelGGL(traj_mfma, grid, block, 0, stream,
                       obs, noise, scene, W_emb, b_emb,
                       Wih_e, Whh_e, b_e, W_h, b_h, W_c, b_c,
                       Wih_d, Whh_d, b_d, W_out, b_out, out);
}

// Round 9
// 441.951 us; speedup vs baseline: 2.0904x; 1.0157x over previous
//
#include <hip/hip_runtime.h>
#include <cstddef>

#define OBS_LEN  20
#define PRED_LEN 30

typedef __attribute__((ext_vector_type(8))) short short8v;  // 8 bf16 (4 VGPRs)
typedef __attribute__((ext_vector_type(4))) float f32x4;

__device__ __forceinline__ float sigm(float x) {
    return __builtin_amdgcn_rcpf(1.0f + __expf(-x));
}
__device__ __forceinline__ float tanh_f(float x) {
    return fmaf(2.0f, sigm(2.0f * x), -1.0f);
}
// branchless RNE f32->bf16 (4 int ops, no libcall)
__device__ __forceinline__ unsigned short f2bf_rne(float x) {
    const unsigned u = __builtin_bit_cast(unsigned, x);
    return (unsigned short)((u + 0x7FFFu + ((u >> 16) & 1u)) >> 16);
}
__device__ __forceinline__ short8v ldw8(const float* __restrict__ p) {
    const float4 a = *(const float4*)(p);
    const float4 b = *(const float4*)(p + 4);
    uint4 w;
    w.x = (unsigned)f2bf_rne(a.x) | ((unsigned)f2bf_rne(a.y) << 16);
    w.y = (unsigned)f2bf_rne(a.z) | ((unsigned)f2bf_rne(a.w) << 16);
    w.z = (unsigned)f2bf_rne(b.x) | ((unsigned)f2bf_rne(b.y) << 16);
    w.w = (unsigned)f2bf_rne(b.z) | ((unsigned)f2bf_rne(b.w) << 16);
    return __builtin_bit_cast(short8v, w);
}
// per-lane embed: 8 units (rows 8q..8q+7) of one batch row -> A-fragment
__device__ __forceinline__ short8v embed8(float x0, float x1,
        const float wE0[8], const float wE1[8], const float bE[8]) {
    unsigned short s[8];
#pragma unroll
    for (int j = 0; j < 8; ++j) {
        const float e = fmaxf(0.f, fmaf(wE0[j], x0, fmaf(wE1[j], x1, bE[j])));
        s[j] = f2bf_rne(e);
    }
    uint4 w;
    w.x = (unsigned)s[0] | ((unsigned)s[1] << 16);
    w.y = (unsigned)s[2] | ((unsigned)s[3] << 16);
    w.z = (unsigned)s[4] | ((unsigned)s[5] << 16);
    w.w = (unsigned)s[6] | ((unsigned)s[7] << 16);
    return __builtin_bit_cast(short8v, w);
}

#define MFMA(A, B, C) __builtin_amdgcn_mfma_f32_16x16x32_bf16((A), (B), (C), 0, 0, 0)

// R8 structure, three changes:
//  (a) LDS 56.8 -> 53.9KB: 163840/53900 = 3.04 -> 3 blocks/CU (3 waves/SIMD),
//      regalloc budget 512/3 = 170 > our 128 -> still no spill.
//  (b) decoder barrier A deleted: every wave computes the identical y-MFMA,
//      writes its OWN y_lds copy, reads it back after lgkmcnt (intra-wave
//      RAW through LDS needs no __syncthreads).
//  (c) y history staged in LDS, one fully-coalesced flush at the end
//      (kills the 8B/240B-stride write amplification).
extern "C" __global__ void __launch_bounds__(256, 2)
traj_mfma(const float* __restrict__ obs,   const float* __restrict__ noise,
          const float* __restrict__ scene,
          const float* __restrict__ W_emb, const float* __restrict__ b_emb,
          const float* __restrict__ Wih_e, const float* __restrict__ Whh_e, const float* __restrict__ b_e,
          const float* __restrict__ W_h,   const float* __restrict__ b_h,
          const float* __restrict__ W_c,   const float* __restrict__ b_c,
          const float* __restrict__ Wih_d, const float* __restrict__ Whh_d, const float* __restrict__ b_d,
          const float* __restrict__ W_out, const float* __restrict__ b_out,
          float* __restrict__ out)
{
    __shared__ __align__(16) unsigned short hbuf[2][2][2][1152]; // [tile][buf][hi/lo] 16x72
    __shared__ __align__(16) unsigned short ns_l[2][1536];       // [tile][16*96]
    __shared__ __align__(16) float obs_l[1280];                  // 32 rows x 40 f32
    __shared__ __align__(16) float y_lds[4][2][16][2];           // per-WAVE y copy
    __shared__ __align__(16) float y_hist[32][60];               // staged output
    __shared__ float occ_pad[3875];                              // total 53900B -> 3 blocks/CU

    const int id = threadIdx.x;
    if (blockIdx.x == 0xFFFFFFFFu) { occ_pad[id] = 1.0f; out[id] = occ_pad[id ^ 1]; }

    const int l    = id & 63;
    const int w    = id >> 6;        // wave = gate-column slice
    const int q    = l >> 4;
    const int jm   = l & 15;
    const int colb = w * 16 + jm;    // hidden j in [0,64)
    const int bb   = blockIdx.x * 32;

    // ---------------- one-time register-resident weights ----------------
    short8v Be[3][4], Bd[3][4];
    float bias_e[4], bias_d[4];
#pragma unroll
    for (int t = 0; t < 4; ++t) {
        const int row = t * 64 + colb;
        Be[0][t] = ldw8(Wih_e + row * 32 + 8 * q);
        Be[1][t] = ldw8(Whh_e + row * 64 + 8 * q);
        Be[2][t] = ldw8(Whh_e + row * 64 + 32 + 8 * q);
        Bd[0][t] = ldw8(Wih_d + row * 32 + 8 * q);
        Bd[1][t] = ldw8(Whh_d + row * 64 + 8 * q);
        Bd[2][t] = ldw8(Whh_d + row * 64 + 32 + 8 * q);
        bias_e[t] = b_e[row];
        bias_d[t] = b_d[row];
    }
    // W_out as B-fragment: col = jm (0/1 valid), k = 8q..
    short8v Bo0, Bo1;
    {
        const short8v z = {0, 0, 0, 0, 0, 0, 0, 0};
        if (jm < 2) {
            Bo0 = ldw8(W_out + jm * 64 + 8 * q);
            Bo1 = ldw8(W_out + jm * 64 + 32 + 8 * q);
        } else { Bo0 = z; Bo1 = z; }
    }
    // per-lane embed weights: units 8q..8q+7
    float wE0[8], wE1[8], bE[8];
#pragma unroll
    for (int j = 0; j < 8; ++j) {
        wE0[j] = W_emb[(8 * q + j) * 2];
        wE1[j] = W_emb[(8 * q + j) * 2 + 1];
        bE[j]  = b_emb[8 * q + j];
    }
    const float bo0 = b_out[0], bo1 = b_out[1];

    // init h=0, stage obs (32 rows)
    {
        unsigned* hz = (unsigned*)&hbuf[0][0][0][0];
        for (int k2 = id; k2 < 4608; k2 += 256) hz[k2] = 0u;
        for (int k2 = id; k2 < 1280; k2 += 256) obs_l[k2] = obs[(size_t)bb * 40 + k2];
    }
    float c[2][4];
#pragma unroll
    for (int p = 0; p < 2; ++p)
#pragma unroll
        for (int r = 0; r < 4; ++r) c[p][r] = 0.f;
    __syncthreads();

    int cur = 0;

    // store hi/lo via truncation (lo captures the exact residual)
#define H_STORE(nh, nl, hv, rr)                                              \
    {                                                                        \
        const unsigned uh = __builtin_bit_cast(unsigned, (hv));              \
        (nh)[(4 * q + (rr)) * 72 + colb] = (unsigned short)(uh >> 16);       \
        const float lo = (hv) - __builtin_bit_cast(float, uh & 0xFFFF0000u); \
        (nl)[(4 * q + (rr)) * 72 + colb] =                                   \
            (unsigned short)(__builtin_bit_cast(unsigned, lo) >> 16);        \
    }

    // ==================== encoder (1 barrier/step) ====================
#pragma unroll 1
    for (int t = 0; t < OBS_LEN; ++t) {
        const short8v AeA = embed8(obs_l[jm * 40 + 2 * t], obs_l[jm * 40 + 2 * t + 1],
                                   wE0, wE1, bE);
        const short8v AeB = embed8(obs_l[(16 + jm) * 40 + 2 * t], obs_l[(16 + jm) * 40 + 2 * t + 1],
                                   wE0, wE1, bE);
        const short8v H1A = *(const short8v*)(&hbuf[0][cur][0][jm * 72 + 8 * q]);
        const short8v H2A = *(const short8v*)(&hbuf[0][cur][0][jm * 72 + 32 + 8 * q]);
        const short8v L1A = *(const short8v*)(&hbuf[0][cur][1][jm * 72 + 8 * q]);
        const short8v L2A = *(const short8v*)(&hbuf[0][cur][1][jm * 72 + 32 + 8 * q]);
        const short8v H1B = *(const short8v*)(&hbuf[1][cur][0][jm * 72 + 8 * q]);
        const short8v H2B = *(const short8v*)(&hbuf[1][cur][0][jm * 72 + 32 + 8 * q]);
        const short8v L1B = *(const short8v*)(&hbuf[1][cur][1][jm * 72 + 8 * q]);
        const short8v L2B = *(const short8v*)(&hbuf[1][cur][1][jm * 72 + 32 + 8 * q]);

        f32x4 gA[4], gB[4];
#pragma unroll
        for (int t4 = 0; t4 < 4; ++t4) {
            f32x4 a = {bias_e[t4], bias_e[t4], bias_e[t4], bias_e[t4]};
            f32x4 b = a;
            a = MFMA(AeA, Be[0][t4], a);  b = MFMA(AeB, Be[0][t4], b);
            a = MFMA(H1A, Be[1][t4], a);  b = MFMA(H1B, Be[1][t4], b);
            a = MFMA(H2A, Be[2][t4], a);  b = MFMA(H2B, Be[2][t4], b);
            a = MFMA(L1A, Be[1][t4], a);  b = MFMA(L1B, Be[1][t4], b);
            a = MFMA(L2A, Be[2][t4], a);  b = MFMA(L2B, Be[2][t4], b);
            gA[t4] = a; gB[t4] = b;
        }
#pragma unroll
        for (int p = 0; p < 2; ++p) {
            unsigned short* nh = &hbuf[p][cur ^ 1][0][0];
            unsigned short* nl = &hbuf[p][cur ^ 1][1][0];
#pragma unroll
            for (int r = 0; r < 4; ++r) {
                const f32x4* g = (p == 0) ? gA : gB;
                const float ig = sigm(g[0][r]);
                const float fg = sigm(g[1][r]);
                const float gg = tanh_f(g[2][r]);
                const float og = sigm(g[3][r]);
                c[p][r] = fmaf(fg, c[p][r], ig * gg);
                const float hv = og * tanh_f(c[p][r]);
                H_STORE(nh, nl, hv, r);
            }
        }
        __syncthreads();
        cur ^= 1;
    }

    // ==================== cond -> decoder init ====================
    {
        {   // stage [noise | scene | 0] as bf16
            const int i2 = id >> 4, cb = (id & 15) * 6;
#pragma unroll
            for (int p = 0; p < 2; ++p) {
                const int row = bb + p * 16 + i2;
#pragma unroll
                for (int cc = 0; cc < 6; ++cc) {
                    const int col = cb + cc;
                    float v;
                    if (col < 16)      v = noise[(size_t)row * 16 + col];
                    else if (col < 80) v = scene[(size_t)row * 64 + (col - 16)];
                    else               v = 0.f;
                    ns_l[p][i2 * 96 + col] = f2bf_rne(v);
                }
            }
        }
        __syncthreads();

        const short8v A0A = *(const short8v*)(&hbuf[0][cur][0][jm * 72 + 8 * q]);
        const short8v A1A = *(const short8v*)(&hbuf[0][cur][0][jm * 72 + 32 + 8 * q]);
        const short8v L0A = *(const short8v*)(&hbuf[0][cur][1][jm * 72 + 8 * q]);
        const short8v L1A = *(const short8v*)(&hbuf[0][cur][1][jm * 72 + 32 + 8 * q]);
        const short8v A0B = *(const short8v*)(&hbuf[1][cur][0][jm * 72 + 8 * q]);
        const short8v A1B = *(const short8v*)(&hbuf[1][cur][0][jm * 72 + 32 + 8 * q]);
        const short8v L0B = *(const short8v*)(&hbuf[1][cur][1][jm * 72 + 8 * q]);
        const short8v L1B = *(const short8v*)(&hbuf[1][cur][1][jm * 72 + 32 + 8 * q]);
        const short8v N0A = *(const short8v*)(&ns_l[0][jm * 96 + 8 * q]);
        const short8v N1A = *(const short8v*)(&ns_l[0][jm * 96 + 32 + 8 * q]);
        const short8v N2A = *(const short8v*)(&ns_l[0][jm * 96 + 64 + 8 * q]);
        const short8v N0B = *(const short8v*)(&ns_l[1][jm * 96 + 8 * q]);
        const short8v N1B = *(const short8v*)(&ns_l[1][jm * 96 + 32 + 8 * q]);
        const short8v N2B = *(const short8v*)(&ns_l[1][jm * 96 + 64 + 8 * q]);
        const short8v zfrag = {0, 0, 0, 0, 0, 0, 0, 0};

        {   // h0
            short8v Bf[5];
#pragma unroll
            for (int kt = 0; kt < 4; ++kt)
                Bf[kt] = ldw8(W_h + (size_t)colb * 144 + kt * 32 + 8 * q);
            Bf[4] = (q < 2) ? ldw8(W_h + (size_t)colb * 144 + 128 + 8 * q) : zfrag;
            f32x4 ahA = {b_h[colb], b_h[colb], b_h[colb], b_h[colb]};
            f32x4 ahB = ahA;
            ahA = MFMA(A0A, Bf[0], ahA);  ahB = MFMA(A0B, Bf[0], ahB);
            ahA = MFMA(A1A, Bf[1], ahA);  ahB = MFMA(A1B, Bf[1], ahB);
            ahA = MFMA(L0A, Bf[0], ahA);  ahB = MFMA(L0B, Bf[0], ahB);
            ahA = MFMA(L1A, Bf[1], ahA);  ahB = MFMA(L1B, Bf[1], ahB);
            ahA = MFMA(N0A, Bf[2], ahA);  ahB = MFMA(N0B, Bf[2], ahB);
            ahA = MFMA(N1A, Bf[3], ahA);  ahB = MFMA(N1B, Bf[3], ahB);
            ahA = MFMA(N2A, Bf[4], ahA);  ahB = MFMA(N2B, Bf[4], ahB);
#pragma unroll
            for (int p = 0; p < 2; ++p) {
                unsigned short* nh = &hbuf[p][cur ^ 1][0][0];
                unsigned short* nl = &hbuf[p][cur ^ 1][1][0];
#pragma unroll
                for (int r = 0; r < 4; ++r) {
                    const float hv = (p == 0) ? ahA[r] : ahB[r];
                    H_STORE(nh, nl, hv, r);
                }
            }
        }
        {   // c0
            short8v Bf[5];
#pragma unroll
            for (int kt = 0; kt < 4; ++kt)
                Bf[kt] = ldw8(W_c + (size_t)colb * 144 + kt * 32 + 8 * q);
            Bf[4] = (q < 2) ? ldw8(W_c + (size_t)colb * 144 + 128 + 8 * q) : zfrag;
            f32x4 acA = {b_c[colb], b_c[colb], b_c[colb], b_c[colb]};
            f32x4 acB = acA;
            acA = MFMA(A0A, Bf[0], acA);  acB = MFMA(A0B, Bf[0], acB);
            acA = MFMA(A1A, Bf[1], acA);  acB = MFMA(A1B, Bf[1], acB);
            acA = MFMA(L0A, Bf[0], acA);  acB = MFMA(L0B, Bf[0], acB);
            acA = MFMA(L1A, Bf[1], acA);  acB = MFMA(L1B, Bf[1], acB);
            acA = MFMA(N0A, Bf[2], acA);  acB = MFMA(N0B, Bf[2], acB);
            acA = MFMA(N1A, Bf[3], acA);  acB = MFMA(N1B, Bf[3], acB);
            acA = MFMA(N2A, Bf[4], acA);  acB = MFMA(N2B, Bf[4], acB);
#pragma unroll
            for (int r = 0; r < 4; ++r) { c[0][r] = acA[r]; c[1][r] = acB[r]; }
        }
        __syncthreads();
        cur ^= 1;
    }

    // ==================== decoder (1 barrier/step) ====================
#pragma unroll 1
    for (int t = 0; t < PRED_LEN; ++t) {
        const short8v H1A = *(const short8v*)(&hbuf[0][cur][0][jm * 72 + 8 * q]);
        const short8v H2A = *(const short8v*)(&hbuf[0][cur][0][jm * 72 + 32 + 8 * q]);
        const short8v L1A = *(const short8v*)(&hbuf[0][cur][1][jm * 72 + 8 * q]);
        const short8v L2A = *(const short8v*)(&hbuf[0][cur][1][jm * 72 + 32 + 8 * q]);
        const short8v H1B = *(const short8v*)(&hbuf[1][cur][0][jm * 72 + 8 * q]);
        const short8v H2B = *(const short8v*)(&hbuf[1][cur][0][jm * 72 + 32 + 8 * q]);
        const short8v L1B = *(const short8v*)(&hbuf[1][cur][1][jm * 72 + 8 * q]);
        const short8v L2B = *(const short8v*)(&hbuf[1][cur][1][jm * 72 + 32 + 8 * q]);

        float xA0, xA1, xB0, xB1;
        if (t == 0) {
            xA0 = obs_l[jm * 40 + 38];        xA1 = obs_l[jm * 40 + 39];
            xB0 = obs_l[(16 + jm) * 40 + 38]; xB1 = obs_l[(16 + jm) * 40 + 39];
        } else {
            // y_{t-1}: every wave computes the SAME MFMA -> use own-wave LDS copy
            f32x4 yA = {0.f, 0.f, 0.f, 0.f}, yB = {0.f, 0.f, 0.f, 0.f};
            yA = MFMA(H1A, Bo0, yA);  yB = MFMA(H1B, Bo0, yB);
            yA = MFMA(H2A, Bo1, yA);  yB = MFMA(H2B, Bo1, yB);
            yA = MFMA(L1A, Bo0, yA);  yB = MFMA(L1B, Bo0, yB);
            yA = MFMA(L2A, Bo1, yA);  yB = MFMA(L2B, Bo1, yB);
            if (jm < 2) {
#pragma unroll
                for (int r = 0; r < 4; ++r) {
                    y_lds[w][0][4 * q + r][jm] = yA[r];
                    y_lds[w][1][4 * q + r][jm] = yB[r];
                }
            }
            if (w == 0 && jm < 2) {   // record history (biased) for final flush
                const float bo = (jm == 0) ? bo0 : bo1;
#pragma unroll
                for (int r = 0; r < 4; ++r) {
                    y_hist[4 * q + r][(t - 1) * 2 + jm]      = yA[r] + bo;
                    y_hist[16 + 4 * q + r][(t - 1) * 2 + jm] = yB[r] + bo;
                }
            }
            asm volatile("s_waitcnt lgkmcnt(0)" ::: "memory");
            __builtin_amdgcn_sched_barrier(0);
            xA0 = y_lds[w][0][jm][0] + bo0;  xA1 = y_lds[w][0][jm][1] + bo1;
            xB0 = y_lds[w][1][jm][0] + bo0;  xB1 = y_lds[w][1][jm][1] + bo1;
        }
        const short8v AeA = embed8(xA0, xA1, wE0, wE1, bE);
        const short8v AeB = embed8(xB0, xB1, wE0, wE1, bE);

        f32x4 gA[4], gB[4];
#pragma unroll
        for (int t4 = 0; t4 < 4; ++t4) {
            f32x4 a = {bias_d[t4], bias_d[t4], bias_d[t4], bias_d[t4]};
            f32x4 b = a;
            a = MFMA(AeA, Bd[0][t4], a);  b = MFMA(AeB, Bd[0][t4], b);
            a = MFMA(H1A, Bd[1][t4], a);  b = MFMA(H1B, Bd[1][t4], b);
            a = MFMA(H2A, Bd[2][t4], a);  b = MFMA(H2B, Bd[2][t4], b);
            a = MFMA(L1A, Bd[1][t4], a);  b = MFMA(L1B, Bd[1][t4], b);
            a = MFMA(L2A, Bd[2][t4], a);  b = MFMA(L2B, Bd[2][t4], b);
            gA[t4] = a; gB[t4] = b;
        }
#pragma unroll
        for (int p = 0; p < 2; ++p) {
            unsigned short* nh = &hbuf[p][cur ^ 1][0][0];
            unsigned short* nl = &hbuf[p][cur ^ 1][1][0];
#pragma unroll
            for (int r = 0; r < 4; ++r) {
                const f32x4* g = (p == 0) ? gA : gB;
                const float ig = sigm(g[0][r]);
                const float fg = sigm(g[1][r]);
                const float gg = tanh_f(g[2][r]);
                const float og = sigm(g[3][r]);
                c[p][r] = fmaf(fg, c[p][r], ig * gg);
                const float hv = og * tanh_f(c[p][r]);
                H_STORE(nh, nl, hv, r);
            }
        }
        __syncthreads();   // hbuf[cur^1] + y_hist visible
        cur ^= 1;
    }

    // ==================== final y (pred 29) from h_30 ====================
    {
        const short8v H1A = *(const short8v*)(&hbuf[0][cur][0][jm * 72 + 8 * q]);
        const short8v H2A = *(const short8v*)(&hbuf[0][cur][0][jm * 72 + 32 + 8 * q]);
        const short8v L1A = *(const short8v*)(&hbuf[0][cur][1][jm * 72 + 8 * q]);
        const short8v L2A = *(const short8v*)(&hbuf[0][cur][1][jm * 72 + 32 + 8 * q]);
        const short8v H1B = *(const short8v*)(&hbuf[1][cur][0][jm * 72 + 8 * q]);
        const short8v H2B = *(const short8v*)(&hbuf[1][cur][0][jm * 72 + 32 + 8 * q]);
        const short8v L1B = *(const short8v*)(&hbuf[1][cur][1][jm * 72 + 8 * q]);
        const short8v L2B = *(const short8v*)(&hbuf[1][cur][1][jm * 72 + 32 + 8 * q]);
        f32x4 yA = {0.f, 0.f, 0.f, 0.f}, yB = {0.f, 0.f, 0.f, 0.f};
        yA = MFMA(H1A, Bo0, yA);  yB = MFMA(H1B, Bo0, yB);
        yA = MFMA(H2A, Bo1, yA);  yB = MFMA(H2B, Bo1, yB);
        yA = MFMA(L1A, Bo0, yA);  yB = MFMA(L1B, Bo0, yB);
        yA = MFMA(L2A, Bo1, yA);  yB = MFMA(L2B, Bo1, yB);
        if (w == 0 && jm < 2) {
            const float bo = (jm == 0) ? bo0 : bo1;
#pragma unroll
            for (int r = 0; r < 4; ++r) {
                y_hist[4 * q + r][(PRED_LEN - 1) * 2 + jm]      = yA[r] + bo;
                y_hist[16 + 4 * q + r][(PRED_LEN - 1) * 2 + jm] = yB[r] + bo;
            }
        }
        __syncthreads();
        // coalesced flush: 32 rows x 60 f32 = 1920 contiguous floats
        float* op = out + (size_t)bb * 60;
        const float* yh = &y_hist[0][0];
        for (int k2 = id; k2 < 1920; k2 += 256) op[k2] = yh[k2];
    }
#undef H_STORE
}

extern "C" void kernel_launch(void* const* d_in, const int* in_sizes, int n_in,
                              void* d_out, int out_size, void* d_ws, size_t ws_size,
                              hipStream_t stream) {
    (void)in_sizes; (void)n_in; (void)d_ws; (void)ws_size; (void)out_size;
    const float* obs    = (const float*)d_in[0];
    const float* noise  = (const float*)d_in[1];
    const float* scene  = (const float*)d_in[2];
    const float* W_emb  = (const float*)d_in[3];
    const float* b_emb  = (const float*)d_in[4];
    const float* Wih_e  = (const float*)d_in[5];
    const float* Whh_e  = (const float*)d_in[6];
    const float* b_e    = (const float*)d_in[7];
    const float* W_h    = (const float*)d_in[8];
    const float* b_h    = (const float*)d_in[9];
    const float* W_c    = (const float*)d_in[10];
    const float* b_c    = (const float*)d_in[11];
    const float* Wih_d  = (const float*)d_in[12];
    const float* Whh_d  = (const float*)d_in[13];
    const float* b_d    = (const float*)d_in[14];
    const float* W_out  = (const float*)d_in[15];
    const float* b_out  = (const float*)d_in[16];
    float* out = (float*)d_out;

    dim3 grid(65536 / 32), block(256);
    hipLaunchKernelGGL(traj_mfma, grid, block, 0, stream,
                       obs, noise, scene, W_emb, b_emb,
                       Wih_e, Whh_e, b_e, W_h, b_h, W_c, b_c,
                       Wih_d, Whh_d, b_d, W_out, b_out, out);
}